// Round 2
// baseline (1041.489 us; speedup 1.0000x reference)
//
#include <hip/hip_runtime.h>
#include <math.h>

#define T_NO   200
#define C_NO   63
#define E_NO   2000
#define I_NO   500
#define TD     50000
#define TPAD   50048
#define EPSF   1e-8f

// workspace layout (float offsets)
#define WS_HE    0            // 63*200 = 12600
#define WS_HI    12600        // 63*200
#define WS_HOBS  25200        // 63*401 = 25263 (end 50463)
#define WS_SYNE  50464        // 64*50048 = 3203072
#define WS_SYNI  3253536      // 64*50048
#define WS_L0T   6456608      // 63*50048 = 3153024 (end 9609632 floats = 38.4 MB)

// padded LDS map: +4 words every 32 data words -> lane-stride-4 b128 reads are
// conflict-free (group m lands in 16B-column (m + m/8) mod 8, a Latin square)
#define PADW(w) ((w) + (((w) >> 5) << 2))

// ---------------- K1: filter banks (matches numpy float64 basis build) ----------
__global__ void filters_kernel(const float* __restrict__ Wsyn,   // (63,13,2)
                               const float* __restrict__ Wobs,   // (63,25)
                               float* __restrict__ ws) {
    const double PI = 3.14159265358979323846;
    int idx = blockIdx.x * blockDim.x + threadIdx.x;
    int stride = gridDim.x * blockDim.x;

    for (int p = idx; p < 63 * 200; p += stride) {
        int c = p / 200, d = p - c * 200;
        double raw = 5.0 * log((double)d + 1.0 + 1e-8);
        float ae = 0.f, ai = 0.f;
        for (int b = 0; b < 13; ++b) {
            double phi = 0.5 * PI * (double)b;
            float bv = 0.f;
            if (raw >= phi - PI && raw <= phi + PI)
                bv = (float)(0.5 * cos(raw - phi) + 0.5);
            ae += Wsyn[(c * 13 + b) * 2 + 0] * bv;
            ai += Wsyn[(c * 13 + b) * 2 + 1] * bv;
        }
        ws[WS_HE + p] = ae;
        ws[WS_HI + p] = ai;
    }

    for (int p = idx; p < 63 * 401; p += stride) {
        int c = p / 401, d = p - c * 401;
        double raw = 5.0 * log(fabs((double)(d - 200)) + 1.0 + 1e-8);
        float acc = 0.f;
        for (int i = 0; i < 13; ++i) {
            double phi = 0.5 * PI * (double)i;
            float bv = 0.f;
            if (raw >= phi - PI && raw <= phi + PI)
                bv = (float)(0.5 * cos(raw - phi) + 0.5);
            float w;
            if (i == 0) {
                w = Wobs[c * 25];
            } else {
                w = 0.f;
                if (d >= 200) w += Wobs[c * 25 + 2 * i - 1];
                if (d <= 200) w += Wobs[c * 25 + 2 * i];
            }
            acc += w * bv;
        }
        ws[WS_HOBS + p] = acc;
    }
}

// ---------------- K2: fused skinny GEMMs, split-K, atomic accumulate ----------
// grid (782, 2 kHalves, 2 matrices); 64t x 64c tile, BK=32, reg double-buffer.
__global__ __launch_bounds__(256) void gemm_kernel(const float* __restrict__ S_e,
                                                   const float* __restrict__ S_i,
                                                   const float* __restrict__ Ce,
                                                   const float* __restrict__ Ci,
                                                   float* __restrict__ synE,
                                                   float* __restrict__ synI) {
    __shared__ float As[32 * 68];
    __shared__ float Bs[32 * 68];
    const int bz = blockIdx.z;
    const float* S  = bz ? S_i : S_e;
    const float* Cs = bz ? Ci : Ce;
    float* synT     = bz ? synI : synE;
    const int K     = bz ? I_NO : E_NO;
    int kbeg, kend;
    if (bz == 0) { kbeg = blockIdx.y ? 1000 : 0; kend = kbeg + 1000; }
    else         { kbeg = blockIdx.y ? 256 : 0;  kend = blockIdx.y ? 500 : 256; }

    const int tid = threadIdx.x;
    const int ty = tid >> 4, tx = tid & 15;
    const int t0 = blockIdx.x * 64;

    // staging decomposition: l in {tid, tid+256}; r = l>>3 (0..63), kg = (l&7)*4
    const int r0 = tid >> 3,          kg0 = (tid & 7) << 2;
    const int r1 = (tid + 256) >> 3,  kg1 = kg0;

    const int nk = (kend - kbeg + 31) / 32;
    float4 pa0, pb0, pa1, pb1;

    auto prefetch = [&](int kc) {
        const int kb = kbeg + kc * 32;
        float4 z = {0.f, 0.f, 0.f, 0.f};
        int k0 = kb + kg0;
        int ta = t0 + r0;
        pa0 = (ta < TD && k0 < kend) ? *(const float4*)(S + (size_t)ta * K + k0) : z;
        pb0 = (r0 < 63 && k0 < kend) ? *(const float4*)(Cs + (size_t)(r0 + 1) * K + k0) : z;
        int tb = t0 + r1;
        pa1 = (tb < TD && k0 < kend) ? *(const float4*)(S + (size_t)tb * K + k0) : z;
        pb1 = (r1 < 63 && k0 < kend) ? *(const float4*)(Cs + (size_t)(r1 + 1) * K + k0) : z;
    };

    float acc[4][4] = {};
    prefetch(0);
    for (int kc = 0; kc < nk; ++kc) {
        __syncthreads();   // previous compute done, LDS reusable
        As[(kg0 + 0) * 68 + r0] = pa0.x;
        As[(kg0 + 1) * 68 + r0] = pa0.y;
        As[(kg0 + 2) * 68 + r0] = pa0.z;
        As[(kg0 + 3) * 68 + r0] = pa0.w;
        Bs[(kg0 + 0) * 68 + r0] = pb0.x;
        Bs[(kg0 + 1) * 68 + r0] = pb0.y;
        Bs[(kg0 + 2) * 68 + r0] = pb0.z;
        Bs[(kg0 + 3) * 68 + r0] = pb0.w;
        As[(kg1 + 0) * 68 + r1] = pa1.x;
        As[(kg1 + 1) * 68 + r1] = pa1.y;
        As[(kg1 + 2) * 68 + r1] = pa1.z;
        As[(kg1 + 3) * 68 + r1] = pa1.w;
        Bs[(kg1 + 0) * 68 + r1] = pb1.x;
        Bs[(kg1 + 1) * 68 + r1] = pb1.y;
        Bs[(kg1 + 2) * 68 + r1] = pb1.z;
        Bs[(kg1 + 3) * 68 + r1] = pb1.w;
        __syncthreads();
        if (kc + 1 < nk) prefetch(kc + 1);
        #pragma unroll
        for (int kk = 0; kk < 32; ++kk) {
            const float4 a = *(const float4*)&As[kk * 68 + 4 * ty];
            const float4 b = *(const float4*)&Bs[kk * 68 + 4 * tx];
            float av[4] = {a.x, a.y, a.z, a.w};
            float bv[4] = {b.x, b.y, b.z, b.w};
            #pragma unroll
            for (int i = 0; i < 4; ++i)
                #pragma unroll
                for (int j = 0; j < 4; ++j)
                    acc[i][j] += av[i] * bv[j];
        }
    }
    #pragma unroll
    for (int j = 0; j < 4; ++j) {
        int c = 4 * tx + j;
        if (c < 63) {
            #pragma unroll
            for (int i = 0; i < 4; ++i)
                atomicAdd(synT + (size_t)c * TPAD + t0 + 4 * ty + i, acc[i][j]);
        }
    }
}

// ---------------- K3: FIR, sliding-register-window, 4 consecutive t/thread ----
__device__ inline float4 ldg4(const float* s, int m) {
    return *(const float4*)(s + 4 * m + ((m >> 3) << 2));
}

__global__ __launch_bounds__(256) void fir_kernel(const float* __restrict__ synE,
                                                  const float* __restrict__ synI,
                                                  const float* __restrict__ Z,
                                                  const float* __restrict__ he,
                                                  const float* __restrict__ hi,
                                                  const float* __restrict__ ho,
                                                  const float* __restrict__ Theta,
                                                  float* __restrict__ L0T) {
    __shared__ __align__(16) float sE[1392];     // 1228 data words padded
    __shared__ __align__(16) float sI[1392];
    __shared__ __align__(16) float zs[1616];     // 1428 data words padded
    __shared__ __align__(16) float heS[200];
    __shared__ __align__(16) float hiS[200];
    __shared__ __align__(16) float hoS[404];

    const int c   = blockIdx.y;
    const int t0  = blockIdx.x * 1024;
    const int tid = threadIdx.x;
    const int base = t0 - 203;

    for (int w = tid; w < 1228; w += 256) {
        int t = base + w;
        bool ok = (t >= 0 && t < TD);
        size_t idx = (size_t)c * TPAD + t;
        sE[PADW(w)] = ok ? synE[idx] : 0.f;
        sI[PADW(w)] = ok ? synI[idx] : 0.f;
    }
    for (int w = tid; w < 1428; w += 256) {
        int t = base + w;
        zs[PADW(w)] = (t >= 0 && t < TD) ? Z[t] : 0.f;
    }
    for (int d = tid; d < 200; d += 256) { heS[d] = he[c * 200 + d]; hiS[d] = hi[c * 200 + d]; }
    for (int d = tid; d < 401; d += 256) hoS[d] = ho[c * 401 + d];
    __syncthreads();

    const float th = Theta[c];
    float acc[4] = {th, th, th, th};

    // e/i FIR: 200 taps = 50 groups of 4; window groups m0 = tid - dg + 50, m0+1
    {
        float4 eLo = ldg4(sE, tid + 50), eHi = ldg4(sE, tid + 51);
        float4 iLo = ldg4(sI, tid + 50), iHi = ldg4(sI, tid + 51);
        for (int dg = 0; dg < 50; ++dg) {
            const float4 h_e = *(const float4*)(heS + 4 * dg);
            const float4 h_i = *(const float4*)(hiS + 4 * dg);
            const float ew[8] = {eLo.x, eLo.y, eLo.z, eLo.w, eHi.x, eHi.y, eHi.z, eHi.w};
            const float iw[8] = {iLo.x, iLo.y, iLo.z, iLo.w, iHi.x, iHi.y, iHi.z, iHi.w};
            const float heq[4] = {h_e.x, h_e.y, h_e.z, h_e.w};
            const float hiq[4] = {h_i.x, h_i.y, h_i.z, h_i.w};
            #pragma unroll
            for (int q = 0; q < 4; ++q)
                #pragma unroll
                for (int r = 0; r < 4; ++r) {
                    const int o = 3 + r - q;
                    acc[r] += ew[o] * heq[q] + iw[o] * hiq[q];
                }
            eHi = eLo; iHi = iLo;
            if (dg < 49) { eLo = ldg4(sE, tid + 49 - dg); iLo = ldg4(sI, tid + 49 - dg); }
        }
    }
    // obs FIR: taps 0..399 = 100 groups; window groups m0 = tid - dg + 100, m0+1
    {
        float4 zLo = ldg4(zs, tid + 100), zHi = ldg4(zs, tid + 101);
        for (int dg = 0; dg < 100; ++dg) {
            const float4 h_o = *(const float4*)(hoS + 4 * dg);
            const float zw[8] = {zLo.x, zLo.y, zLo.z, zLo.w, zHi.x, zHi.y, zHi.z, zHi.w};
            const float hoq[4] = {h_o.x, h_o.y, h_o.z, h_o.w};
            #pragma unroll
            for (int q = 0; q < 4; ++q)
                #pragma unroll
                for (int r = 0; r < 4; ++r) {
                    const int o = 3 + r - q;
                    acc[r] += zw[o] * hoq[q];
                }
            zHi = zLo;
            if (dg < 99) zLo = ldg4(zs, tid + 99 - dg);
        }
        // tap d = 400: z word w = 4*tid + 3 + r
        const float h400 = hoS[400];
        #pragma unroll
        for (int r = 0; r < 4; ++r) {
            int w = 4 * tid + 3 + r;
            acc[r] += zs[PADW(w)] * h400;
        }
    }

    const int tb = t0 + 4 * tid;
    if (tb + 3 < TD) {
        float4 v = {acc[0], acc[1], acc[2], acc[3]};
        *(float4*)(L0T + (size_t)c * TPAD + tb) = v;
    } else {
        #pragma unroll
        for (int r = 0; r < 4; ++r)
            if (tb + r < TD) L0T[(size_t)c * TPAD + tb + r] = acc[r];
    }
}

// ---------------- K4: transpose [c][t] -> [t][c] + Gumbel softmax + sigmoid ---
__global__ __launch_bounds__(256) void out_kernel(const float* __restrict__ L0T,
                                                  const float* __restrict__ u,
                                                  const float* __restrict__ temp_p,
                                                  float* __restrict__ out) {
    __shared__ float tile[63 * 65];
    const int t0 = blockIdx.x * 64;
    const int tid = threadIdx.x;

    for (int l = tid; l < 1008; l += 256) {
        int cc = l >> 4;
        int jg = (l & 15) << 2;
        float4 v = *(const float4*)(L0T + (size_t)cc * TPAD + t0 + jg);
        tile[cc * 65 + jg + 0] = v.x;
        tile[cc * 65 + jg + 1] = v.y;
        tile[cc * 65 + jg + 2] = v.z;
        tile[cc * 65 + jg + 3] = v.w;
    }
    __syncthreads();

    const float inv_temp = 1.f / (*temp_p);
    for (int l = tid; l < 4032; l += 256) {
        int tl = l / 63;
        int cc = l - tl * 63;
        int t = t0 + tl;
        if (t < TD) {
            float L0 = tile[cc * 65 + tl];
            float2 uv = *(const float2*)(u + 2 * ((size_t)t * 63 + cc));
            float g0 = -logf(-logf(uv.x + EPSF) + EPSF);
            float g1 = -logf(-logf(uv.y + EPSF) + EPSF);
            float zh = 1.f / (1.f + expf(-((L0 + g0 - g1) * inv_temp)));
            float sg = 1.f / (1.f + expf(-L0));
            out[(size_t)t * 63 + cc] = zh;
            out[3150000 + (size_t)t * 63 + cc] = sg;
        }
    }
}

extern "C" void kernel_launch(void* const* d_in, const int* in_sizes, int n_in,
                              void* d_out, int out_size, void* d_ws, size_t ws_size,
                              hipStream_t stream) {
    (void)in_sizes; (void)n_in; (void)out_size; (void)ws_size;
    const float* S_e   = (const float*)d_in[0];
    const float* S_i   = (const float*)d_in[1];
    const float* Z     = (const float*)d_in[2];
    const float* temp  = (const float*)d_in[3];
    const float* u     = (const float*)d_in[4];
    const float* Ce    = (const float*)d_in[5];
    const float* Ci    = (const float*)d_in[6];
    const float* Wsyn  = (const float*)d_in[7];
    const float* Wobs  = (const float*)d_in[8];
    const float* Theta = (const float*)d_in[9];
    float* out = (float*)d_out;
    float* ws  = (float*)d_ws;

    float* he   = ws + WS_HE;
    float* hi   = ws + WS_HI;
    float* ho   = ws + WS_HOBS;
    float* synE = ws + WS_SYNE;
    float* synI = ws + WS_SYNI;
    float* L0T  = ws + WS_L0T;

    hipLaunchKernelGGL(filters_kernel, dim3(50), dim3(256), 0, stream, Wsyn, Wobs, ws);
    // zero syn accumulators (split-K atomics accumulate into them)
    hipMemsetAsync(synE, 0, (size_t)(2 * 3203072) * sizeof(float), stream);
    hipLaunchKernelGGL(gemm_kernel, dim3(782, 2, 2), dim3(256), 0, stream,
                       S_e, S_i, Ce, Ci, synE, synI);
    hipLaunchKernelGGL(fir_kernel, dim3(49, 63), dim3(256), 0, stream,
                       synE, synI, Z, he, hi, ho, Theta, L0T);
    hipLaunchKernelGGL(out_kernel, dim3(782), dim3(256), 0, stream, L0T, u, temp, out);
}

// Round 3
// 1021.336 us; speedup vs baseline: 1.0197x; 1.0197x over previous
//
#include <hip/hip_runtime.h>
#include <math.h>

#define T_NO   200
#define C_NO   63
#define E_NO   2000
#define I_NO   500
#define TD     50000
#define TPAD   50048
#define EPSF   1e-8f

typedef float f32x4 __attribute__((ext_vector_type(4)));
typedef short s16x8 __attribute__((ext_vector_type(8)));

// ws layout (float offsets)
#define WS_HE    0              // 63*200
#define WS_HI    12600          // 63*200
#define WS_HOBS  25200          // 63*401 -> 50463
#define WS_COSB  50464          // 13*200 -> 53064
#define WS_OBSB  53064          // 25*401 -> 63089
#define WS_BE    63104          // bf16 64*2048 (65536 floats) -> 128640
#define WS_BI    128640         // bf16 64*512  (16384 floats) -> 145024
#define WS_PE0   145024         // 3 E partials, 64*TPAD each
#define PBSZ     3203072
#define WS_PI    9754240        // 1 I partial
#define WS_L0T   12957312       // 63*TPAD -> 16110336 floats (~61.5 MB)

// padded LDS map for FIR: +4 words every 32 data words
#define PADW(w) ((w) + (((w) >> 5) << 2))

__device__ inline unsigned short f2bf(float x) {   // RNE fp32->bf16
    unsigned u = __float_as_uint(x);
    return (unsigned short)((u + 0x7FFFu + ((u >> 16) & 1u)) >> 16);
}
__device__ inline unsigned pack2(float lo, float hi) {
    return (unsigned)f2bf(lo) | ((unsigned)f2bf(hi) << 16);
}

// ---------------- K0: raised-cosine bases (double math ONCE per basis point) --
__global__ void basis_kernel(float* __restrict__ ws) {
    const double PI = 3.14159265358979323846;
    int idx = blockIdx.x * blockDim.x + threadIdx.x;
    int stride = gridDim.x * blockDim.x;
    for (int p = idx; p < 13 * 200; p += stride) {
        int i = p / 200, t = p - i * 200;
        double raw = 5.0 * log((double)t + 1.0 + 1e-8);
        double phi = 0.5 * PI * (double)i;
        float b = (raw >= phi - PI && raw <= phi + PI) ? (float)(0.5 * cos(raw - phi) + 0.5) : 0.f;
        ws[WS_COSB + p] = b;
    }
    for (int p = idx; p < 25 * 401; p += stride) {
        int j = p / 401, x = p - j * 401;
        int i = (j + 1) >> 1;
        double raw = 5.0 * log(fabs((double)(x - 200)) + 1.0 + 1e-8);
        double phi = 0.5 * PI * (double)i;
        float b = (raw >= phi - PI && raw <= phi + PI) ? (float)(0.5 * cos(raw - phi) + 0.5) : 0.f;
        if (j > 0) {
            if (j & 1) { if (x < 200) b = 0.f; }   // row 2i-1: keep x>=200
            else       { if (x > 200) b = 0.f; }   // row 2i:   keep x<=200
        }
        ws[WS_OBSB + p] = b;
    }
}

// ---------------- K1: weight filters + pre-convert B matrices to bf16 --------
__global__ void prep_kernel(const float* __restrict__ Wsyn, const float* __restrict__ Wobs,
                            const float* __restrict__ Ce, const float* __restrict__ Ci,
                            float* __restrict__ ws) {
    int idx = blockIdx.x * blockDim.x + threadIdx.x;
    int stride = gridDim.x * blockDim.x;
    for (int p = idx; p < 63 * 200; p += stride) {
        int c = p / 200, t = p - c * 200;
        float ae = 0.f, ai = 0.f;
        #pragma unroll
        for (int b = 0; b < 13; ++b) {
            float bv = ws[WS_COSB + b * 200 + t];
            ae += Wsyn[(c * 13 + b) * 2 + 0] * bv;
            ai += Wsyn[(c * 13 + b) * 2 + 1] * bv;
        }
        ws[WS_HE + p] = ae;
        ws[WS_HI + p] = ai;
    }
    for (int p = idx; p < 63 * 401; p += stride) {
        int c = p / 401, x = p - c * 401;
        float a = 0.f;
        #pragma unroll
        for (int j = 0; j < 25; ++j)
            a += Wobs[c * 25 + j] * ws[WS_OBSB + j * 401 + x];
        ws[WS_HOBS + p] = a;
    }
    unsigned short* Be = (unsigned short*)(ws + WS_BE);
    for (int p = idx; p < 64 * 2048; p += stride) {
        int c = p >> 11, k = p & 2047;
        float v = (c < 63 && k < E_NO) ? Ce[(size_t)(c + 1) * E_NO + k] : 0.f;
        Be[p] = f2bf(v);
    }
    unsigned short* Bi = (unsigned short*)(ws + WS_BI);
    for (int p = idx; p < 64 * 512; p += stride) {
        int c = p >> 9, k = p & 511;
        float v = (c < 63 && k < I_NO) ? Ci[(size_t)(c + 1) * I_NO + k] : 0.f;
        Bi[p] = f2bf(v);
    }
}

// ---------------- K2: bf16 MFMA GEMM, 128t x 64c tile, split-K partials ------
// grid (391, 4): y<3 -> E chunk y (K 672 each over 2016-pad); y==3 -> I.
#define LDA 40   // bf16 row stride in LDS (80 B: 16B-aligned, 2-way banks max)
__global__ __launch_bounds__(128, 4) void gemm_kernel(const float* __restrict__ S_e,
                                                      const float* __restrict__ S_i,
                                                      float* __restrict__ ws) {
    __shared__ unsigned int Asu[128 * 20];   // 128 rows x 40 bf16
    __shared__ unsigned int Bsu[64 * 20];

    const int y = blockIdx.y;
    const bool isE = (y < 3);
    const float* S = isE ? S_e : S_i;
    const unsigned short* Bm = (const unsigned short*)(ws + (isE ? WS_BE : WS_BI));
    const int K     = isE ? E_NO : I_NO;
    const int Kpad  = isE ? 2048 : 512;
    const int kb    = isE ? y * 672 : 0;
    const int nst   = isE ? 21 : 16;
    float* outp = ws + (isE ? (WS_PE0 + (size_t)y * PBSZ) : WS_PI);

    const int tid  = threadIdx.x;
    const int lane = tid & 63;
    const int w    = tid >> 6;            // wave 0..1
    const int t0   = blockIdx.x * 128;

    // A staging: one row per thread
    const int tA = t0 + tid;
    const float* Srow = S + (size_t)tA * K;
    // B staging: c=tid&63, k-half seg
    const int bc = tid & 63, bseg = tid >> 6;

    unsigned au[16];   // 32 bf16 packed (one A row, BK=32)
    unsigned pbv[8];   // 16 bf16 (B)

    auto pf = [&](int s) {
        const int kk = kb + 32 * s;
        #pragma unroll
        for (int g = 0; g < 8; ++g) {
            int k = kk + 4 * g;
            float4 v = {0.f, 0.f, 0.f, 0.f};
            if (tA < TD && k < K) v = *(const float4*)(Srow + k);
            au[2 * g]     = pack2(v.x, v.y);
            au[2 * g + 1] = pack2(v.z, v.w);
        }
        const uint4* bp = (const uint4*)(Bm + (size_t)bc * Kpad + kk + bseg * 16);
        uint4 b0 = bp[0], b1 = bp[1];
        pbv[0] = b0.x; pbv[1] = b0.y; pbv[2] = b0.z; pbv[3] = b0.w;
        pbv[4] = b1.x; pbv[5] = b1.y; pbv[6] = b1.z; pbv[7] = b1.w;
    };

    f32x4 acc[4][4] = {};   // [t-tile][c-tile], 16x16 each
    pf(0);
    for (int s = 0; s < nst; ++s) {
        __syncthreads();
        uint4* ap = (uint4*)(Asu + tid * 20);
        ap[0] = make_uint4(au[0], au[1], au[2], au[3]);
        ap[1] = make_uint4(au[4], au[5], au[6], au[7]);
        ap[2] = make_uint4(au[8], au[9], au[10], au[11]);
        ap[3] = make_uint4(au[12], au[13], au[14], au[15]);
        uint4* bp2 = (uint4*)(Bsu + bc * 20 + bseg * 8);
        bp2[0] = make_uint4(pbv[0], pbv[1], pbv[2], pbv[3]);
        bp2[1] = make_uint4(pbv[4], pbv[5], pbv[6], pbv[7]);
        __syncthreads();
        if (s + 1 < nst) pf(s + 1);

        const unsigned short* As = (const unsigned short*)Asu;
        const unsigned short* Bs = (const unsigned short*)Bsu;
        const int klocal = (lane >> 4) * 8;            // quad*8
        s16x8 af[4], bf[4];
        #pragma unroll
        for (int ta = 0; ta < 4; ++ta) {
            int row = 64 * w + 16 * ta + (lane & 15);
            af[ta] = *(const s16x8*)(As + row * LDA + klocal);
        }
        #pragma unroll
        for (int cb = 0; cb < 4; ++cb) {
            int col = 16 * cb + (lane & 15);
            bf[cb] = *(const s16x8*)(Bs + col * LDA + klocal);
        }
        #pragma unroll
        for (int ta = 0; ta < 4; ++ta)
            #pragma unroll
            for (int cb = 0; cb < 4; ++cb)
                acc[ta][cb] = __builtin_amdgcn_mfma_f32_16x16x32_bf16(af[ta], bf[cb], acc[ta][cb], 0, 0, 0);
    }

    // epilogue: C/D layout col=lane&15, row=4*(lane>>4)+reg  (m89-verified)
    const int cl = lane & 15, rq = 4 * (lane >> 4);
    #pragma unroll
    for (int ta = 0; ta < 4; ++ta)
        #pragma unroll
        for (int cb = 0; cb < 4; ++cb) {
            int c = 16 * cb + cl;
            float* dst = outp + (size_t)c * TPAD + t0 + 64 * w + 16 * ta + rq;
            f32x4 v = acc[ta][cb];
            *(float4*)dst = make_float4(v.x, v.y, v.z, v.w);
        }
}

// ---------------- K3: FIR (sums 3 E partials + 1 I partial) -------------------
__device__ inline float4 ldg4(const float* s, int m) {
    return *(const float4*)(s + 4 * m + ((m >> 3) << 2));
}

__global__ __launch_bounds__(256) void fir_kernel(const float* __restrict__ pE0,
                                                  const float* __restrict__ pE1,
                                                  const float* __restrict__ pE2,
                                                  const float* __restrict__ pI0,
                                                  const float* __restrict__ Z,
                                                  const float* __restrict__ he,
                                                  const float* __restrict__ hi,
                                                  const float* __restrict__ ho,
                                                  const float* __restrict__ Theta,
                                                  float* __restrict__ L0T) {
    __shared__ __align__(16) float sE[1392];
    __shared__ __align__(16) float sI[1392];
    __shared__ __align__(16) float zs[1616];
    __shared__ __align__(16) float heS[200];
    __shared__ __align__(16) float hiS[200];
    __shared__ __align__(16) float hoS[404];

    const int c   = blockIdx.y;
    const int t0  = blockIdx.x * 1024;
    const int tid = threadIdx.x;
    const int base = t0 - 203;

    for (int w = tid; w < 1228; w += 256) {
        int t = base + w;
        bool ok = (t >= 0 && t < TD);
        size_t idx = (size_t)c * TPAD + t;
        float ve = 0.f, vi = 0.f;
        if (ok) {
            ve = pE0[idx] + pE1[idx] + pE2[idx];
            vi = pI0[idx];
        }
        sE[PADW(w)] = ve;
        sI[PADW(w)] = vi;
    }
    for (int w = tid; w < 1428; w += 256) {
        int t = base + w;
        zs[PADW(w)] = (t >= 0 && t < TD) ? Z[t] : 0.f;
    }
    for (int d = tid; d < 200; d += 256) { heS[d] = he[c * 200 + d]; hiS[d] = hi[c * 200 + d]; }
    for (int d = tid; d < 401; d += 256) hoS[d] = ho[c * 401 + d];
    __syncthreads();

    const float th = Theta[c];
    float acc[4] = {th, th, th, th};

    {
        float4 eLo = ldg4(sE, tid + 50), eHi = ldg4(sE, tid + 51);
        float4 iLo = ldg4(sI, tid + 50), iHi = ldg4(sI, tid + 51);
        for (int dg = 0; dg < 50; ++dg) {
            const float4 h_e = *(const float4*)(heS + 4 * dg);
            const float4 h_i = *(const float4*)(hiS + 4 * dg);
            const float ew[8] = {eLo.x, eLo.y, eLo.z, eLo.w, eHi.x, eHi.y, eHi.z, eHi.w};
            const float iw[8] = {iLo.x, iLo.y, iLo.z, iLo.w, iHi.x, iHi.y, iHi.z, iHi.w};
            const float heq[4] = {h_e.x, h_e.y, h_e.z, h_e.w};
            const float hiq[4] = {h_i.x, h_i.y, h_i.z, h_i.w};
            #pragma unroll
            for (int q = 0; q < 4; ++q)
                #pragma unroll
                for (int r = 0; r < 4; ++r) {
                    const int o = 3 + r - q;
                    acc[r] += ew[o] * heq[q] + iw[o] * hiq[q];
                }
            eHi = eLo; iHi = iLo;
            if (dg < 49) { eLo = ldg4(sE, tid + 49 - dg); iLo = ldg4(sI, tid + 49 - dg); }
        }
    }
    {
        float4 zLo = ldg4(zs, tid + 100), zHi = ldg4(zs, tid + 101);
        for (int dg = 0; dg < 100; ++dg) {
            const float4 h_o = *(const float4*)(hoS + 4 * dg);
            const float zw[8] = {zLo.x, zLo.y, zLo.z, zLo.w, zHi.x, zHi.y, zHi.z, zHi.w};
            const float hoq[4] = {h_o.x, h_o.y, h_o.z, h_o.w};
            #pragma unroll
            for (int q = 0; q < 4; ++q)
                #pragma unroll
                for (int r = 0; r < 4; ++r) {
                    const int o = 3 + r - q;
                    acc[r] += zw[o] * hoq[q];
                }
            zHi = zLo;
            if (dg < 99) zLo = ldg4(zs, tid + 99 - dg);
        }
        const float h400 = hoS[400];
        #pragma unroll
        for (int r = 0; r < 4; ++r) {
            int w = 4 * tid + 3 + r;
            acc[r] += zs[PADW(w)] * h400;
        }
    }

    const int tb = t0 + 4 * tid;
    if (tb + 3 < TD) {
        float4 v = {acc[0], acc[1], acc[2], acc[3]};
        *(float4*)(L0T + (size_t)c * TPAD + tb) = v;
    } else {
        #pragma unroll
        for (int r = 0; r < 4; ++r)
            if (tb + r < TD) L0T[(size_t)c * TPAD + tb + r] = acc[r];
    }
}

// ---------------- K4: transpose + Gumbel softmax + sigmoid --------------------
__global__ __launch_bounds__(256) void out_kernel(const float* __restrict__ L0T,
                                                  const float* __restrict__ u,
                                                  const float* __restrict__ temp_p,
                                                  float* __restrict__ out) {
    __shared__ float tile[63 * 65];
    const int t0 = blockIdx.x * 64;
    const int tid = threadIdx.x;

    for (int l = tid; l < 1008; l += 256) {
        int cc = l >> 4;
        int jg = (l & 15) << 2;
        float4 v = *(const float4*)(L0T + (size_t)cc * TPAD + t0 + jg);
        tile[cc * 65 + jg + 0] = v.x;
        tile[cc * 65 + jg + 1] = v.y;
        tile[cc * 65 + jg + 2] = v.z;
        tile[cc * 65 + jg + 3] = v.w;
    }
    __syncthreads();

    const float inv_temp = 1.f / (*temp_p);
    for (int l = tid; l < 4032; l += 256) {
        int tl = l / 63;
        int cc = l - tl * 63;
        int t = t0 + tl;
        if (t < TD) {
            float L0 = tile[cc * 65 + tl];
            float2 uv = *(const float2*)(u + 2 * ((size_t)t * 63 + cc));
            float g0 = -logf(-logf(uv.x + EPSF) + EPSF);
            float g1 = -logf(-logf(uv.y + EPSF) + EPSF);
            float zh = 1.f / (1.f + expf(-((L0 + g0 - g1) * inv_temp)));
            float sg = 1.f / (1.f + expf(-L0));
            out[(size_t)t * 63 + cc] = zh;
            out[3150000 + (size_t)t * 63 + cc] = sg;
        }
    }
}

extern "C" void kernel_launch(void* const* d_in, const int* in_sizes, int n_in,
                              void* d_out, int out_size, void* d_ws, size_t ws_size,
                              hipStream_t stream) {
    (void)in_sizes; (void)n_in; (void)out_size; (void)ws_size;
    const float* S_e   = (const float*)d_in[0];
    const float* S_i   = (const float*)d_in[1];
    const float* Z     = (const float*)d_in[2];
    const float* temp  = (const float*)d_in[3];
    const float* u     = (const float*)d_in[4];
    const float* Ce    = (const float*)d_in[5];
    const float* Ci    = (const float*)d_in[6];
    const float* Wsyn  = (const float*)d_in[7];
    const float* Wobs  = (const float*)d_in[8];
    const float* Theta = (const float*)d_in[9];
    float* out = (float*)d_out;
    float* ws  = (float*)d_ws;

    hipLaunchKernelGGL(basis_kernel, dim3(50), dim3(256), 0, stream, ws);
    hipLaunchKernelGGL(prep_kernel, dim3(256), dim3(256), 0, stream, Wsyn, Wobs, Ce, Ci, ws);
    hipLaunchKernelGGL(gemm_kernel, dim3(391, 4), dim3(128), 0, stream, S_e, S_i, ws);
    hipLaunchKernelGGL(fir_kernel, dim3(49, 63), dim3(256), 0, stream,
                       ws + WS_PE0, ws + WS_PE0 + PBSZ, ws + WS_PE0 + 2 * (size_t)PBSZ,
                       ws + WS_PI, Z,
                       ws + WS_HE, ws + WS_HI, ws + WS_HOBS, Theta, ws + WS_L0T);
    hipLaunchKernelGGL(out_kernel, dim3(782), dim3(256), 0, stream, ws + WS_L0T, u, temp, out);
}